// Round 7
// baseline (234.336 us; speedup 1.0000x reference)
//
#include <hip/hip_runtime.h>
#include <stdint.h>

// ---------------------------------------------------------------------------
// BinaryLinear: out[M,N] = x[M,K] @ sign(W[N,K])^T + bias[N]
// M=8192, K=2048, N=2048, fp32 in/out.
// Round 11: break the CU-wide lockstep (measured: MFMA+LDS windows sum-
// serialize at 2890cyc/K32-step = the 890TF plateau).
//   - B (+-1 bf16) read straight from global L2 into registers (panel is
//     L2-resident: same-bn blocks share an XCD). No B in LDS: LDS reads
//     -33%, staging -50%, LDS 64KB.
//   - NO mid-tile barriers: per K-tile the interior free-runs (HW scoreboards
//     order frag-read->MFMA per wave); one sched_barrier(0)+vmcnt(0)+s_barrier
//     per tile certifies staged A + B regs (2-phase lag => free; R8 data).
//   - A LDS: 2 bufs x 256x64 bf16; swizzle chunk ^= ((row&1)<<2)|((row>>1)&3)
//     — conflict-free under the 16-lane-group bank model that explains both
//     R10's measured 0 and R7/R8's measured 4.0/read.
//   - B regs ping-pong b0/b1 via 2-tile loop unroll (constant indexing only,
//     rule #20). 16x16x32 MFMA, acc[8][4], direct-store epilogue (verified).
//   - prep: cvt_x re-coalesced to unit-stride (float4 in, uint2 out).
// ---------------------------------------------------------------------------

typedef __bf16 bf16x8 __attribute__((ext_vector_type(8)));
typedef float f32x4 __attribute__((ext_vector_type(4)));

typedef const __attribute__((address_space(1))) void* gas_ptr;
typedef __attribute__((address_space(3))) void* lds_ptr;

__device__ __forceinline__ unsigned short f2bf_rne(float f) {
    unsigned int u = __builtin_bit_cast(unsigned int, f);
    u += 0x7fffu + ((u >> 16) & 1u);   // round-to-nearest-even
    return (unsigned short)(u >> 16);
}

// Merged prep, both halves strictly unit-stride:
//  blocks [0,nxB): x fp32 -> bf16 bits, 4/thread (float4 load, uint2 store).
//  blocks [nxB,..): W fp32 -> sign(W) bf16 +-1, 4/thread (same shape).
__global__ __launch_bounds__(256) void prep_kernel(
    const float* __restrict__ x, const float* __restrict__ w,
    unsigned short* __restrict__ xb, unsigned short* __restrict__ wb,
    int nx4, int nxB, int nw4)
{
    const int b = blockIdx.x;
    if (b < nxB) {
        int i = b * 256 + threadIdx.x;
        if (i >= nx4) return;
        float4 f = reinterpret_cast<const float4*>(x)[i];
        union { unsigned short s[4]; uint2 v; } o;
        o.s[0] = f2bf_rne(f.x); o.s[1] = f2bf_rne(f.y);
        o.s[2] = f2bf_rne(f.z); o.s[3] = f2bf_rne(f.w);
        reinterpret_cast<uint2*>(xb)[i] = o.v;
    } else {
        int i = (b - nxB) * 256 + threadIdx.x;
        if (i >= nw4) return;
        float4 f = reinterpret_cast<const float4*>(w)[i];
        union { unsigned short s[4]; uint2 v; } o;
        o.s[0] = (f.x >= 0.f) ? 0x3F80u : 0xBF80u;
        o.s[1] = (f.y >= 0.f) ? 0x3F80u : 0xBF80u;
        o.s[2] = (f.z >= 0.f) ? 0x3F80u : 0xBF80u;
        o.s[3] = (f.w >= 0.f) ? 0x3F80u : 0xBF80u;
        reinterpret_cast<uint2*>(wb)[i] = o.v;
    }
}

#define WAITVM0   asm volatile("s_waitcnt vmcnt(0)")
#define SBAR      __builtin_amdgcn_s_barrier()
#define SCHEDB    __builtin_amdgcn_sched_barrier(0)

__global__ __launch_bounds__(512, 2) void gemm_bin_kernel(
    const unsigned short* __restrict__ A,   // bf16 bits [M][K]
    const unsigned short* __restrict__ B,   // bf16 bits [N][K] (+-1)
    const float* __restrict__ bias,         // [N]
    float* __restrict__ C,                  // [M][N]
    int M, int N, int K)
{
    // A only: 2 buffers x (256 rows x 64 bf16) = 64 KB.
    __shared__ __align__(16) unsigned char smem_raw[65536];
    unsigned short* const sm = (unsigned short*)smem_raw;

    const int tid  = threadIdx.x;
    const int lane = tid & 63;
    const int wave = tid >> 6;    // 0..7
    const int wm   = wave >> 2;   // 0..1  (M half: 128 rows)
    const int wn   = wave & 3;    // 0..3  (N quarter: 64 cols)
    const int bm   = blockIdx.y;  // 32
    const int bn   = blockIdx.x;  // 8

    const unsigned short* __restrict__ Agb = A + (size_t)(bm * 256) * K;

    const int r15 = lane & 15;    // frag row (A) / col (B)
    const int kc  = lane >> 4;    // k-chunk 0..3 within K=32 slice
    const int msk = ((r15 & 1) << 2) | ((r15 >> 1) & 3);   // bank-spread XOR

    // A frag offsets (ushort, buffer-relative): row = wm*128 + mf*16 + r15,
    // 64 ushort/row, chunk (kc + 4*kk) ^ msk. mf folded as +mf*1024.
    const int offA0 = (wm * 128 + r15) * 64 + ((kc    ) ^ msk) * 8;
    const int offA1 = (wm * 128 + r15) * 64 + ((kc + 4) ^ msk) * 8;

    // Staging (per half-tile of 128 rows): 1024 chunks, 2/thread; LDS dest
    // linear, global col pre-swizzled with the same involution.
    int gsoff[2], ldoff[2];
#pragma unroll
    for (int j = 0; j < 2; ++j) {
        const int g  = j * 512 + tid;
        const int rl = g >> 3;
        const int pc = g & 7;
        const int ml = ((rl & 1) << 2) | ((rl >> 1) & 3);
        gsoff[j] = rl * K + (pc ^ ml) * 8;
        ldoff[j] = g * 8;
    }

    const int colb = bn * 256 + wn * 64;
    float bv[4];
#pragma unroll
    for (int nf = 0; nf < 4; ++nf) {
        bv[nf] = bias[colb + nf * 16 + r15];
        asm volatile("" :: "v"(bv[nf]));
    }

    // B row pointers (global, L2-resident): row = colb + nf*16 + r15.
    const unsigned short* Bg[4];
#pragma unroll
    for (int nf = 0; nf < 4; ++nf)
        Bg[nf] = B + (size_t)(colb + nf * 16 + r15) * K + kc * 8;

    f32x4 acc[8][4];
#pragma unroll
    for (int m = 0; m < 8; ++m)
#pragma unroll
        for (int n = 0; n < 4; ++n)
#pragma unroll
            for (int r = 0; r < 4; ++r) acc[m][n][r] = 0.f;

    bf16x8 b0[4][2], b1[4][2];   // B frag ping-pong (constant-indexed only)

    auto stageH = [&](int T, int h, unsigned short* buf) {
        const unsigned short* g = Agb + (size_t)(h * 128) * K + (size_t)T * 64;
        unsigned short* d = buf + h * 8192;
#pragma unroll
        for (int j = 0; j < 2; ++j)
            __builtin_amdgcn_global_load_lds((gas_ptr)(g + gsoff[j]),
                                             (lds_ptr)(d + ldoff[j]), 16, 0, 0);
    };
    auto loadB = [&](int T, bf16x8 (&dst)[4][2]) {
#pragma unroll
        for (int nf = 0; nf < 4; ++nf)
#pragma unroll
            for (int kk = 0; kk < 2; ++kk)
                dst[nf][kk] = *reinterpret_cast<const bf16x8*>(
                    Bg[nf] + (size_t)T * 64 + kk * 32);
    };

    // One K-tile: interior runs barrier-free; single certification at end.
    auto tileBody = [&](int T, const unsigned short* bb, unsigned short* nb,
                        bf16x8 (&bc)[4][2], bf16x8 (&bn_)[4][2], bool pf) {
        if (pf) {
            stageH(T + 1, 0, nb);
            stageH(T + 1, 1, nb);
            loadB(T + 1, bn_);
        }
#pragma unroll
        for (int p = 0; p < 4; ++p) {
            bf16x8 af[2][2];
#pragma unroll
            for (int mi = 0; mi < 2; ++mi) {
                af[mi][0] = *reinterpret_cast<const bf16x8*>(bb + offA0 + (p * 2 + mi) * 1024);
                af[mi][1] = *reinterpret_cast<const bf16x8*>(bb + offA1 + (p * 2 + mi) * 1024);
            }
            __builtin_amdgcn_s_setprio(1);
#pragma unroll
            for (int kk = 0; kk < 2; ++kk)
#pragma unroll
                for (int mi = 0; mi < 2; ++mi)
#pragma unroll
                    for (int nf = 0; nf < 4; ++nf)
                        acc[p * 2 + mi][nf] = __builtin_amdgcn_mfma_f32_16x16x32_bf16(
                            af[mi][kk], bc[nf][kk], acc[p * 2 + mi][nf], 0, 0, 0);
            __builtin_amdgcn_s_setprio(0);
        }
        SCHEDB;            // pin stages/reads/MFMAs before the certification
        WAITVM0;           // certify stage(T+1)+B(T+1): >=1-tile lag => free
        SBAR;              // publish to all waves
    };

    const int KT = K >> 6;   // 32 K-tiles of 64

    // Prologue: tile 0 staged + B(0) regs; certify; sync.
    stageH(0, 0, sm);
    stageH(0, 1, sm);
    loadB(0, b0);
    SCHEDB;
    WAITVM0;
    SBAR;

    for (int T2 = 0; T2 < KT; T2 += 2) {
        tileBody(T2,     sm,         sm + 16384, b0, b1, true);
        tileBody(T2 + 1, sm + 16384, sm,         b1, b0, T2 + 2 < KT);
    }

    // Epilogue: direct stores. 16x16 C/D: col = lane&15, row = (lane>>4)*4+reg.
    const int row0 = bm * 256 + wm * 128 + kc * 4;
#pragma unroll
    for (int mf = 0; mf < 8; ++mf)
#pragma unroll
        for (int nf = 0; nf < 4; ++nf) {
            float* cp = C + (size_t)(row0 + mf * 16) * N + colb + nf * 16 + r15;
#pragma unroll
            for (int r = 0; r < 4; ++r)
                cp[(size_t)r * N] = acc[mf][nf][r] + bv[nf];
        }
}

extern "C" void kernel_launch(void* const* d_in, const int* in_sizes, int n_in,
                              void* d_out, int out_size, void* d_ws, size_t ws_size,
                              hipStream_t stream) {
    const float* x    = (const float*)d_in[0];   // [M, K]
    const float* w    = (const float*)d_in[1];   // [N, K]
    const float* bias = (const float*)d_in[2];   // [N]
    float* out = (float*)d_out;

    const int K = 2048;                 // IN
    const int N = in_sizes[2];          // OUT = 2048
    const int M = in_sizes[0] / K;      // 8192

    unsigned short* xb = (unsigned short*)d_ws;   // [M,K] bf16: 32 MB
    unsigned short* wb = xb + (size_t)M * K;      // [N,K] bf16 +-1: 8 MB

    const int nx4 = (M * K) / 4;
    const int nw4 = (N * K) / 4;
    const int nxB = (nx4 + 255) / 256;
    const int nwB = (nw4 + 255) / 256;
    prep_kernel<<<nxB + nwB, 256, 0, stream>>>(x, w, xb, wb, nx4, nxB, nw4);

    dim3 grid(N / 256, M / 256);        // (8, 32) = 256 blocks, 1/CU
    gemm_bin_kernel<<<grid, 512, 0, stream>>>(xb, wb, bias, out, M, N, K);
}